// Round 4
// baseline (458.569 us; speedup 1.0000x reference)
//
#include <hip/hip_runtime.h>

// Sparsity_Checker: fused passthrough-copy + collector histogram + finalize.
// All four reference outputs derive from the 5-bin histogram of
// collector = sum_t spikes[t] (values 0..T):
//   unique_counts[k]  = hist[k]
//   coll_zero_frac    = hist[0] / total
//   sparsity_ratio    = (total*T - sum_k k*hist[k]) / (total*T)
// Memory-bound: ~205 MB read (partially L3-resident) + ~201 MB write.
// NOTE: nontemporal hints REGRESSED 3-4x on gfx950 (R3: 1.65 TB/s vs plain
// ~5+ TB/s) — nt defeats L3 residency of the harness-restored input. Plain
// cached loads/stores only.

constexpr int T_STEPS = 4;

__global__ __launch_bounds__(256) void spike_stats_kernel(
    const float4* __restrict__ in, float4* __restrict__ out,
    unsigned int* __restrict__ hist,  // hist[0..4] bins, hist[5] done-ticket
    float* __restrict__ tail, int nvec, double total)
{
    __shared__ unsigned int lhist[5];
    __shared__ unsigned int s_prev;
    if (threadIdx.x < 5) lhist[threadIdx.x] = 0u;
    __syncthreads();

    // packed histogram: 5 bins x 12 bits. grid=2048x256 -> <=7 iters/thread,
    // per-wave bin max = 64 lanes * 4 elems * 7 iters = 1792 < 4096. No overflow.
    unsigned long long packed = 0ull;

    const int stride = gridDim.x * blockDim.x;
    for (int v = blockIdx.x * blockDim.x + threadIdx.x; v < nvec; v += stride) {
        float4 a0 = in[0 * nvec + v];
        float4 a1 = in[1 * nvec + v];
        float4 a2 = in[2 * nvec + v];
        float4 a3 = in[3 * nvec + v];
        out[0 * nvec + v] = a0;
        out[1 * nvec + v] = a1;
        out[2 * nvec + v] = a2;
        out[3 * nvec + v] = a3;
        // elements are exactly 0.0f or 1.0f -> sums are exact small ints
        int cx = (int)(a0.x + a1.x + a2.x + a3.x);
        int cy = (int)(a0.y + a1.y + a2.y + a3.y);
        int cz = (int)(a0.z + a1.z + a2.z + a3.z);
        int cw = (int)(a0.w + a1.w + a2.w + a3.w);
        packed += (1ull << (cx * 12)) + (1ull << (cy * 12))
                + (1ull << (cz * 12)) + (1ull << (cw * 12));
    }

    // wave-64 butterfly reduce of the packed histogram
#pragma unroll
    for (int off = 32; off > 0; off >>= 1)
        packed += __shfl_down(packed, off, 64);

    if ((threadIdx.x & 63) == 0) {
#pragma unroll
        for (int k = 0; k < 5; ++k)
            atomicAdd(&lhist[k], (unsigned int)((packed >> (12 * k)) & 0xFFFull));
    }
    __syncthreads();

    // 5 device-scope atomics per block (2048 blocks, 5 addresses) — negligible
    if (threadIdx.x < 5)
        atomicAdd(&hist[threadIdx.x], lhist[threadIdx.x]);
    __syncthreads();  // all 5 hist atomics of this block retired (waitcnt+barrier)

    // last-block-done ticket: the final arriver computes the stats tail
    if (threadIdx.x == 0) {
        __threadfence();                       // order hist adds before ticket
        s_prev = atomicAdd(&hist[5], 1u);
    }
    __syncthreads();
    if (threadIdx.x == 0 && s_prev == gridDim.x - 1) {
        unsigned int h[5];
#pragma unroll
        for (int k = 0; k < 5; ++k)
            h[k] = atomicAdd(&hist[k], 0u);    // coherent device-scope read
        double spikes_sum = 0.0;
#pragma unroll
        for (int k = 0; k < 5; ++k)
            spikes_sum += (double)k * (double)h[k];
        double denom = total * (double)T_STEPS;
        tail[0] = (float)((denom - spikes_sum) / denom); // sparsity_ratio
        tail[1] = (float)((double)h[0] / total);         // coll_zero_frac
#pragma unroll
        for (int k = 0; k < 5; ++k)
            tail[2 + k] = (float)h[k];         // unique_counts (exact: < 2^24)
    }
}

extern "C" void kernel_launch(void* const* d_in, const int* in_sizes, int n_in,
                              void* d_out, int out_size, void* d_ws, size_t ws_size,
                              hipStream_t stream)
{
    const float* spikes = (const float*)d_in[0];
    float* out = (float*)d_out;

    const long n = (long)in_sizes[0];       // T*B*C*H*W = 51,380,224
    const long per_t = n / T_STEPS;         // 12,845,056 elements per timestep
    const int nvec = (int)(per_t / 4);      // 3,211,264 float4 per timestep

    unsigned int* hist = (unsigned int*)d_ws;  // 5 bins + 1 ticket
    (void)hipMemsetAsync(d_ws, 0, 6 * sizeof(unsigned int), stream);

    // grid=2048 (8 blocks/CU): plenty of memory-level parallelism, short tail,
    // packed-histogram overflow bound still safe (see kernel comment).
    spike_stats_kernel<<<dim3(2048), dim3(256), 0, stream>>>(
        (const float4*)spikes, (float4*)out, hist, out + n, nvec, (double)per_t);
}

// Round 5
// 349.807 us; speedup vs baseline: 1.3109x; 1.3109x over previous
//
#include <hip/hip_runtime.h>

// Sparsity_Checker: fused passthrough-copy + collector histogram.
// All four reference outputs derive from the 5-bin histogram of
// collector = sum_t spikes[t] (values 0..T):
//   unique_counts[k]  = hist[k]
//   coll_zero_frac    = hist[0] / total
//   sparsity_ratio    = (total*T - sum_k k*hist[k]) / (total*T)
//
// LESSONS (measured, R3/R4):
//  - __threadfence() (agent fence -> buffer_wbl2/buffer_inv L2 flush) in a
//    last-block-done ticket costs ~2x BW: 2048 staggered L2 invalidations
//    thrash the streaming path. Finalize stays a separate tiny kernel.
//  - __builtin_nontemporal hints also regress (1.65 TB/s) vs plain cached.
// Structure below = Round-1 (fast) + unroll x2 for more loads in flight.

constexpr int T_STEPS = 4;

__global__ __launch_bounds__(256) void spike_stats_kernel(
    const float4* __restrict__ in, float4* __restrict__ out,
    unsigned int* __restrict__ hist, int nvec)
{
    __shared__ unsigned int lhist[5];
    if (threadIdx.x < 5) lhist[threadIdx.x] = 0u;
    __syncthreads();

    // packed histogram: 5 bins x 12 bits. grid=2048x256 -> <=7 grid-stride
    // steps/thread; per-wave bin max = 64 lanes * 4 elems * 7 = 1792 < 4096.
    unsigned long long packed = 0ull;

    const int stride = gridDim.x * blockDim.x;
    const int tid = blockIdx.x * blockDim.x + threadIdx.x;

    for (int v = tid; v < nvec; v += 2 * stride) {
        const int v2 = v + stride;
        const bool has2 = (v2 < nvec);
        // issue all independent loads first (8 outstanding), then stores
        float4 a0 = in[0 * nvec + v];
        float4 a1 = in[1 * nvec + v];
        float4 a2 = in[2 * nvec + v];
        float4 a3 = in[3 * nvec + v];
        float4 b0, b1, b2, b3;
        if (has2) {
            b0 = in[0 * nvec + v2];
            b1 = in[1 * nvec + v2];
            b2 = in[2 * nvec + v2];
            b3 = in[3 * nvec + v2];
        }
        out[0 * nvec + v] = a0;
        out[1 * nvec + v] = a1;
        out[2 * nvec + v] = a2;
        out[3 * nvec + v] = a3;
        // elements are exactly 0.0f or 1.0f -> sums are exact small ints
        int cx = (int)(a0.x + a1.x + a2.x + a3.x);
        int cy = (int)(a0.y + a1.y + a2.y + a3.y);
        int cz = (int)(a0.z + a1.z + a2.z + a3.z);
        int cw = (int)(a0.w + a1.w + a2.w + a3.w);
        packed += (1ull << (cx * 12)) + (1ull << (cy * 12))
                + (1ull << (cz * 12)) + (1ull << (cw * 12));
        if (has2) {
            out[0 * nvec + v2] = b0;
            out[1 * nvec + v2] = b1;
            out[2 * nvec + v2] = b2;
            out[3 * nvec + v2] = b3;
            int dx = (int)(b0.x + b1.x + b2.x + b3.x);
            int dy = (int)(b0.y + b1.y + b2.y + b3.y);
            int dz = (int)(b0.z + b1.z + b2.z + b3.z);
            int dw = (int)(b0.w + b1.w + b2.w + b3.w);
            packed += (1ull << (dx * 12)) + (1ull << (dy * 12))
                    + (1ull << (dz * 12)) + (1ull << (dw * 12));
        }
    }

    // wave-64 butterfly reduce of the packed histogram
#pragma unroll
    for (int off = 32; off > 0; off >>= 1)
        packed += __shfl_down(packed, off, 64);

    if ((threadIdx.x & 63) == 0) {
#pragma unroll
        for (int k = 0; k < 5; ++k)
            atomicAdd(&lhist[k], (unsigned int)((packed >> (12 * k)) & 0xFFFull));
    }
    __syncthreads();

    // 5 relaxed device-scope atomics per block (2048 blocks, 5 addresses)
    if (threadIdx.x < 5)
        atomicAdd(&hist[threadIdx.x], lhist[threadIdx.x]);
}

__global__ void finalize_kernel(const unsigned int* __restrict__ hist,
                                float* __restrict__ tail, double total)
{
    if (threadIdx.x == 0 && blockIdx.x == 0) {
        double spikes_sum = 0.0;
#pragma unroll
        for (int k = 0; k < 5; ++k)
            spikes_sum += (double)k * (double)hist[k];
        double denom = total * (double)T_STEPS;
        tail[0] = (float)((denom - spikes_sum) / denom); // sparsity_ratio
        tail[1] = (float)((double)hist[0] / total);      // coll_zero_frac
#pragma unroll
        for (int k = 0; k < 5; ++k)
            tail[2 + k] = (float)hist[k];                // unique_counts (exact: < 2^24)
    }
}

extern "C" void kernel_launch(void* const* d_in, const int* in_sizes, int n_in,
                              void* d_out, int out_size, void* d_ws, size_t ws_size,
                              hipStream_t stream)
{
    const float* spikes = (const float*)d_in[0];
    float* out = (float*)d_out;

    const long n = (long)in_sizes[0];       // T*B*C*H*W = 51,380,224
    const long per_t = n / T_STEPS;         // 12,845,056 elements per timestep
    const int nvec = (int)(per_t / 4);      // 3,211,264 float4 per timestep

    unsigned int* hist = (unsigned int*)d_ws;
    (void)hipMemsetAsync(d_ws, 0, 5 * sizeof(unsigned int), stream);

    // grid=2048 (8 blocks/CU): plenty of memory-level parallelism, short tail,
    // packed-histogram overflow bound still safe (see kernel comment).
    spike_stats_kernel<<<dim3(2048), dim3(256), 0, stream>>>(
        (const float4*)spikes, (float4*)out, hist, nvec);

    finalize_kernel<<<dim3(1), dim3(64), 0, stream>>>(hist, out + n, (double)per_t);
}